// Round 1
// baseline (83704.944 us; speedup 1.0000x reference)
//
#include <hip/hip_runtime.h>
#include <hip/hip_cooperative_groups.h>

namespace cg = cooperative_groups;

// LSTM: B=64, T=512, D=512, H=1024, gates 4H=4096
// x:[B,T,D] f32, Wx:[D,4H] f32, Wh:[H,4H] f32, b:[4H] f32 -> out:[B,T,H] f32
#define BB   64
#define TT   512
#define DD   512
#define HH   1024
#define G4   4096
#define KT   128          // K tile staged in LDS
#define JB   4            // h-columns per block
#define NBLK (HH / JB)    // 256 blocks, one per CU

__device__ __forceinline__ float sigmoidf_(float v) {
    return 1.0f / (1.0f + __expf(-v));
}

__global__ void __launch_bounds__(256)
lstm_fp32_persist(const float* __restrict__ x,
                  const float* __restrict__ Wx,
                  const float* __restrict__ Wh,
                  const float* __restrict__ bias,
                  float* __restrict__ out,
                  float* __restrict__ ws)
{
    cg::grid_group grid = cg::this_grid();

    __shared__ float sA[BB][KT + 1];   // 64 x 129 fp32, +1 pad: conflict-free column reads
    __shared__ float sG[BB][17];       // gate exchange, 16 cols + pad

    float* h0 = ws;                    // [B][H] fp32, double-buffered h state
    float* h1 = ws + BB * HH;
    float* cb = ws + 2 * BB * HH;      // [B][H] fp32 cell state (block-local ownership)

    const int tid = threadIdx.x;
    const int bid = blockIdx.x;
    const int j0  = bid * JB;          // this block's h-column base

    // zero-init h0 and c (ws is poisoned 0xAA before every launch)
    for (int i = bid * 256 + tid; i < BB * HH; i += NBLK * 256) {
        h0[i] = 0.0f;
        cb[i] = 0.0f;
    }
    grid.sync();

    const int r   = tid & 63;                                   // batch row (lane)
    const int grp = __builtin_amdgcn_readfirstlane(tid >> 6);   // gate id 0..3, wave-uniform -> SGPR
    const int colbase = grp * HH + j0;                          // column into [0,4096)

    // bias for this thread's 4 gate columns (constant across t)
    const float b0 = bias[colbase + 0];
    const float b1 = bias[colbase + 1];
    const float b2 = bias[colbase + 2];
    const float b3 = bias[colbase + 3];

    const float* wxp = Wx + colbase;   // + k*4096 gives row k, cols [colbase, colbase+3]
    const float* whp = Wh + colbase;

    for (int t = 0; t < TT; ++t) {
        const float* hin  = (t & 1) ? h1 : h0;
        float*       hout = (t & 1) ? h0 : h1;

        float a0 = b0, a1 = b1, a2 = b2, a3 = b3;

        // ---- K over x part: gates += x_t @ Wx ----
        for (int k0 = 0; k0 < DD; k0 += KT) {
            __syncthreads();   // previous tile fully consumed
            for (int q = tid; q < BB * (KT / 4); q += 256) {
                const int row = q >> 5;            // KT/4 = 32 float4 per row
                const int kq  = (q & 31) << 2;
                const float4 v = *reinterpret_cast<const float4*>(
                    &x[((size_t)row * TT + t) * DD + k0 + kq]);
                sA[row][kq + 0] = v.x; sA[row][kq + 1] = v.y;
                sA[row][kq + 2] = v.z; sA[row][kq + 3] = v.w;
            }
            __syncthreads();
            const float* wk = wxp + (size_t)k0 * G4;
            #pragma unroll 8
            for (int k = 0; k < KT; ++k) {
                const float a = sA[r][k];
                const float4 w = *reinterpret_cast<const float4*>(wk + (size_t)k * G4);
                a0 = fmaf(a, w.x, a0);
                a1 = fmaf(a, w.y, a1);
                a2 = fmaf(a, w.z, a2);
                a3 = fmaf(a, w.w, a3);
            }
        }

        // ---- K over h part: gates += h @ Wh ----
        for (int k0 = 0; k0 < HH; k0 += KT) {
            __syncthreads();
            for (int q = tid; q < BB * (KT / 4); q += 256) {
                const int row = q >> 5;
                const int kq  = (q & 31) << 2;
                const float4 v = *reinterpret_cast<const float4*>(
                    &hin[row * HH + k0 + kq]);
                sA[row][kq + 0] = v.x; sA[row][kq + 1] = v.y;
                sA[row][kq + 2] = v.z; sA[row][kq + 3] = v.w;
            }
            __syncthreads();
            const float* wk = whp + (size_t)k0 * G4;
            #pragma unroll 8
            for (int k = 0; k < KT; ++k) {
                const float a = sA[r][k];
                const float4 w = *reinterpret_cast<const float4*>(wk + (size_t)k * G4);
                a0 = fmaf(a, w.x, a0);
                a1 = fmaf(a, w.y, a1);
                a2 = fmaf(a, w.z, a2);
                a3 = fmaf(a, w.w, a3);
            }
        }

        // exchange gates so one thread owns all 4 gates of one (b, j)
        __syncthreads();
        sG[r][grp * 4 + 0] = a0;
        sG[r][grp * 4 + 1] = a1;
        sG[r][grp * 4 + 2] = a2;
        sG[r][grp * 4 + 3] = a3;
        __syncthreads();

        {
            const int jj = grp;          // this thread finalizes j = j0 + grp
            const int j  = j0 + jj;
            const float iv = sigmoidf_(sG[r][0 * 4 + jj]);
            const float fv = sigmoidf_(sG[r][1 * 4 + jj]);
            const float gv = tanhf    (sG[r][2 * 4 + jj]);
            const float ov = sigmoidf_(sG[r][3 * 4 + jj]);
            const int idx = r * HH + j;
            const float cold = cb[idx];
            const float cn = fv * cold + iv * gv;
            const float hn = ov * tanhf(cn);
            cb[idx]   = cn;
            hout[idx] = hn;
            out[((size_t)r * TT + t) * HH + j] = hn;
        }
        grid.sync();   // h fully published before any block starts step t+1
    }
}

extern "C" void kernel_launch(void* const* d_in, const int* in_sizes, int n_in,
                              void* d_out, int out_size, void* d_ws, size_t ws_size,
                              hipStream_t stream) {
    const float* x  = (const float*)d_in[0];
    const float* Wx = (const float*)d_in[1];
    const float* Wh = (const float*)d_in[2];
    const float* b  = (const float*)d_in[3];
    float* out = (float*)d_out;
    float* ws  = (float*)d_ws;   // needs 3*64*1024*4 = 768 KB

    void* args[] = { (void*)&x, (void*)&Wx, (void*)&Wh, (void*)&b,
                     (void*)&out, (void*)&ws };
    hipLaunchCooperativeKernel((const void*)lstm_fp32_persist,
                               dim3(NBLK), dim3(256), args, 0, stream);
}

// Round 3
// 22163.715 us; speedup vs baseline: 3.7767x; 3.7767x over previous
//
#include <hip/hip_runtime.h>
#include <hip/hip_cooperative_groups.h>

namespace cg = cooperative_groups;

// LSTM B=64,T=512,D=512,H=1024 ; gates 4H=4096 ; K = D+H = 1536
// 256 blocks = 4 row-tiles (16 batch rows) x 64 col-groups (16 h-cols).
// Block's 64 gate-cols = 4 MFMA col-tiles of 16 "virtual cols" n = gate*4 + jj
//   -> W column (gate*1024 + cgrp*16 + ct*4 + jj). Gate finalize is block-local.
// Weights stay in per-wave VGPR B-fragments (bf16 hi/lo split), loaded ONCE.
// 8 waves = (col-tile ct 0..3) x (K-half kap 0..1); partials reduced via LDS.
// A (=[x_t | h]) is staged twice per step (hi pass, lo pass) into ONE 49 KB
// LDS buffer so total static LDS stays under 64 KB.
#define BB 64
#define TT 512
#define DD 512
#define HH 1024
#define APITCH 1544   // shorts per LDS A row (+8 pad)

typedef __attribute__((ext_vector_type(8))) short sh8;   // 8 bf16 = 4 VGPR (MFMA A/B frag)
typedef __attribute__((ext_vector_type(4))) float f32x4; // MFMA C/D frag

__device__ __forceinline__ unsigned short f2bf(float f) {       // RNE f32->bf16
    union { float f; unsigned u; } v; v.f = f;
    unsigned r = v.u + 0x7FFF + ((v.u >> 16) & 1);
    return (unsigned short)(r >> 16);
}
__device__ __forceinline__ float bf2f(unsigned short h) {
    union { unsigned u; float f; } v; v.u = ((unsigned)h) << 16;
    return v.f;
}
__device__ __forceinline__ float wfull(const float* __restrict__ Wx,
                                       const float* __restrict__ Wh,
                                       int k, int col) {
    return (k < DD) ? Wx[(size_t)k * 4096 + col] : Wh[(size_t)(k - DD) * 4096 + col];
}
__device__ __forceinline__ float sigmoidf_(float v) { return 1.0f / (1.0f + __expf(-v)); }

__global__ void __launch_bounds__(512, 2)
lstm_mfma_persist(const float* __restrict__ x,
                  const float* __restrict__ Wx,
                  const float* __restrict__ Wh,
                  const float* __restrict__ bias,
                  float* __restrict__ out,
                  unsigned short* __restrict__ ws)
{
    cg::grid_group grid = cg::this_grid();

    __shared__ unsigned short sA[16][APITCH];    // 49.4 KB: A hi OR lo (two passes)
    __shared__ float sRed[8][16][17];            // 8.7 KB: per-wave partial C tiles
    __shared__ float sC[16][16];                 // 1 KB: cell state (persists over t)

    unsigned short* hh0 = ws;                    // h hi, buffer 0  [64][1024] bf16 bits
    unsigned short* hl0 = ws + BB * HH;          // h lo, buffer 0
    unsigned short* hh1 = ws + 2 * BB * HH;      // h hi, buffer 1
    unsigned short* hl1 = ws + 3 * BB * HH;      // h lo, buffer 1

    const int tid  = threadIdx.x;
    const int lane = tid & 63;
    const int wid  = tid >> 6;        // 0..7
    const int ct   = wid & 3;         // col-tile within block
    const int kap  = wid >> 2;        // K-half 0/1
    const int rgrp = blockIdx.x >> 6; // 0..3  (16 batch rows)
    const int cgrp = blockIdx.x & 63; // 0..63 (16 h-cols)
    const int rowbase = rgrp * 16;
    const int n  = lane & 15;         // MFMA A-row = B-col within tile
    const int kg = lane >> 4;         // k-group 0..3 (8 contiguous k each)

    // ---- one-time: this wave's B fragments (weights) into VGPRs, split bf16 ----
    const int wcol = (n >> 2) * HH + cgrp * 16 + ct * 4 + (n & 3);
    sh8 bh[24], bl[24];
    #pragma unroll
    for (int f = 0; f < 24; ++f) {
        #pragma unroll
        for (int i = 0; i < 8; ++i) {
            const int k = kap * 768 + f * 32 + kg * 8 + i;
            const float w = wfull(Wx, Wh, k, wcol);
            const unsigned short hi = f2bf(w);
            const unsigned short lo = f2bf(w - bf2f(hi));
            bh[f][i] = (short)hi;
            bl[f][i] = (short)lo;
        }
    }

    // ---- init h buffer 0 + cell state to zero (ws/d_out are poisoned 0xAA) ----
    if (tid < 256) {
        const int r = tid >> 4, c = tid & 15;
        hh0[(rowbase + r) * HH + cgrp * 16 + c] = 0;
        hl0[(rowbase + r) * HH + cgrp * 16 + c] = 0;
        sC[r][c] = 0.0f;
    }

    // finalize lanes (waves 0..3): lane -> (frow, fjj)
    const int frow = lane >> 2, fjj = lane & 3;
    const int gcol = cgrp * 16 + ct * 4 + fjj;   // this lane's h-column
    float bg0 = 0.f, bg1 = 0.f, bg2 = 0.f, bg3 = 0.f;
    if (kap == 0) {
        bg0 = bias[0 * HH + gcol]; bg1 = bias[1 * HH + gcol];
        bg2 = bias[2 * HH + gcol]; bg3 = bias[3 * HH + gcol];
    }
    grid.sync();

    for (int t = 0; t < TT; ++t) {
        const unsigned short* hhc = (t & 1) ? hh1 : hh0;
        const unsigned short* hlc = (t & 1) ? hl1 : hl0;
        unsigned short* hhn = (t & 1) ? hh0 : hh1;
        unsigned short* hln = (t & 1) ? hl0 : hl1;

        f32x4 acc0 = {0.f, 0.f, 0.f, 0.f}, acc1 = {0.f, 0.f, 0.f, 0.f};

        // ================= PASS 1: A-hi =================
        {   // x part: 16 rows x 512 f32 -> bf16 hi
            const int kq = tid & 127;     // *4 floats
            const int r0 = tid >> 7;      // 0..3
            #pragma unroll
            for (int p = 0; p < 4; ++p) {
                const int r = r0 + p * 4;
                const float4 v = *reinterpret_cast<const float4*>(
                    &x[((size_t)(rowbase + r) * TT + t) * DD + kq * 4]);
                ushort4 vh;
                vh.x = f2bf(v.x); vh.y = f2bf(v.y);
                vh.z = f2bf(v.z); vh.w = f2bf(v.w);
                *reinterpret_cast<ushort4*>(&sA[r][kq * 4]) = vh;
            }
        }
        #pragma unroll
        for (int p = 0; p < 8; ++p) {     // h part: straight copy of hi
            const int idx = tid + p * 512;
            const int r  = idx >> 8;
            const int kq = idx & 255;     // *4 shorts
            const ushort4 vh = *reinterpret_cast<const ushort4*>(
                &hhc[(rowbase + r) * HH + kq * 4]);
            *reinterpret_cast<ushort4*>(&sA[r][DD + kq * 4]) = vh;
        }
        __syncthreads();

        #pragma unroll
        for (int f = 0; f < 24; ++f) {    // acc += Ah*Bh + Ah*Bl
            const int k = kap * 768 + f * 32 + kg * 8;
            const sh8 ah = *reinterpret_cast<const sh8*>(&sA[n][k]);
            if (f & 1) {
                acc1 = __builtin_amdgcn_mfma_f32_16x16x32_bf16(ah, bh[f], acc1, 0, 0, 0);
                acc1 = __builtin_amdgcn_mfma_f32_16x16x32_bf16(ah, bl[f], acc1, 0, 0, 0);
            } else {
                acc0 = __builtin_amdgcn_mfma_f32_16x16x32_bf16(ah, bh[f], acc0, 0, 0, 0);
                acc0 = __builtin_amdgcn_mfma_f32_16x16x32_bf16(ah, bl[f], acc0, 0, 0, 0);
            }
        }
        __syncthreads();   // all reads of A-hi done before overwrite

        // ================= PASS 2: A-lo =================
        {   // x part: recompute lo = x - bf2f(hi)
            const int kq = tid & 127;
            const int r0 = tid >> 7;
            #pragma unroll
            for (int p = 0; p < 4; ++p) {
                const int r = r0 + p * 4;
                const float4 v = *reinterpret_cast<const float4*>(
                    &x[((size_t)(rowbase + r) * TT + t) * DD + kq * 4]);
                ushort4 vl;
                vl.x = f2bf(v.x - bf2f(f2bf(v.x)));
                vl.y = f2bf(v.y - bf2f(f2bf(v.y)));
                vl.z = f2bf(v.z - bf2f(f2bf(v.z)));
                vl.w = f2bf(v.w - bf2f(f2bf(v.w)));
                *reinterpret_cast<ushort4*>(&sA[r][kq * 4]) = vl;
            }
        }
        #pragma unroll
        for (int p = 0; p < 8; ++p) {     // h part: straight copy of lo
            const int idx = tid + p * 512;
            const int r  = idx >> 8;
            const int kq = idx & 255;
            const ushort4 vl = *reinterpret_cast<const ushort4*>(
                &hlc[(rowbase + r) * HH + kq * 4]);
            *reinterpret_cast<ushort4*>(&sA[r][DD + kq * 4]) = vl;
        }
        __syncthreads();

        #pragma unroll
        for (int f = 0; f < 24; ++f) {    // acc += Al*Bh
            const int k = kap * 768 + f * 32 + kg * 8;
            const sh8 al = *reinterpret_cast<const sh8*>(&sA[n][k]);
            if (f & 1) acc1 = __builtin_amdgcn_mfma_f32_16x16x32_bf16(al, bh[f], acc1, 0, 0, 0);
            else       acc0 = __builtin_amdgcn_mfma_f32_16x16x32_bf16(al, bh[f], acc0, 0, 0, 0);
        }

        // C/D layout (m89-verified): col = lane&15, row = (lane>>4)*4 + q
        #pragma unroll
        for (int q = 0; q < 4; ++q)
            sRed[wid][kg * 4 + q][n] = acc0[q] + acc1[q];
        __syncthreads();

        // ---- gates + cell update (waves 0..3; wave ct owns its col-tile) ----
        if (kap == 0) {
            const float pi = sRed[ct][frow][ 0 + fjj] + sRed[ct + 4][frow][ 0 + fjj] + bg0;
            const float pf = sRed[ct][frow][ 4 + fjj] + sRed[ct + 4][frow][ 4 + fjj] + bg1;
            const float pg = sRed[ct][frow][ 8 + fjj] + sRed[ct + 4][frow][ 8 + fjj] + bg2;
            const float po = sRed[ct][frow][12 + fjj] + sRed[ct + 4][frow][12 + fjj] + bg3;
            const float iv = sigmoidf_(pi);
            const float fv = sigmoidf_(pf);
            const float gv = tanhf(pg);
            const float ov = sigmoidf_(po);
            const float cold = sC[frow][ct * 4 + fjj];
            const float cn = fv * cold + iv * gv;
            const float hn = ov * tanhf(cn);
            sC[frow][ct * 4 + fjj] = cn;
            const int grow = rowbase + frow;
            out[((size_t)grow * TT + t) * HH + gcol] = hn;
            const unsigned short hi = f2bf(hn);
            const unsigned short lo = f2bf(hn - bf2f(hi));
            hhn[grow * HH + gcol] = hi;
            hln[grow * HH + gcol] = lo;
        }
        grid.sync();   // h_t fully published before any block stages step t+1
    }
}

extern "C" void kernel_launch(void* const* d_in, const int* in_sizes, int n_in,
                              void* d_out, int out_size, void* d_ws, size_t ws_size,
                              hipStream_t stream) {
    const float* x  = (const float*)d_in[0];
    const float* Wx = (const float*)d_in[1];
    const float* Wh = (const float*)d_in[2];
    const float* b  = (const float*)d_in[3];
    float* out = (float*)d_out;
    unsigned short* ws = (unsigned short*)d_ws;  // needs 4 * 64*1024 * 2 B = 512 KB

    void* args[] = { (void*)&x, (void*)&Wx, (void*)&Wh, (void*)&b,
                     (void*)&out, (void*)&ws };
    hipLaunchCooperativeKernel((const void*)lstm_mfma_persist,
                               dim3(256), dim3(512), args, 0, stream);
}

// Round 5
// 7388.483 us; speedup vs baseline: 11.3291x; 2.9998x over previous
//
#include <hip/hip_runtime.h>
#include <hip/hip_cooperative_groups.h>

namespace cg = cooperative_groups;

// LSTM B=64,T=512,D=512,H=1024 ; gates 4H=4096 ; K = D+H = 1536
// 256 blocks = 4 row-cohorts (16 batch rows) x 64 col-groups (16 h-cols).
// Weights stay in per-wave VGPR B-fragments (bf16 hi/lo split), loaded ONCE.
// 8 waves = (col-tile ct 0..3) x (K-half kap 0..1).
// Per step: x-part GEMM (no h dependency) BEFORE a per-cohort flag barrier;
// h-part after. h crosses blocks via packed (hi<<16|lo) uints with
// per-access agent-scope (sc0 sc1) atomics -> no cache flushes, x/W stay hot.
#define BB 64
#define TT 512
#define DD 512
#define HH 1024
#define AP 1032   // sA pitch in shorts (row stride 2064B = 516 banks ≡ 4 mod 32 -> 2-way, free)

typedef __attribute__((ext_vector_type(8))) short sh8;   // 8 bf16 (MFMA A/B frag)
typedef __attribute__((ext_vector_type(4))) float f32x4; // MFMA C/D frag

static __device__ __forceinline__ unsigned short f2bf(float f) {   // RNE f32->bf16
    union { float f; unsigned u; } v; v.f = f;
    unsigned r = v.u + 0x7FFF + ((v.u >> 16) & 1);
    return (unsigned short)(r >> 16);
}
static __device__ __forceinline__ float bf2f(unsigned short h) {
    union { unsigned u; float f; } v; v.u = ((unsigned)h) << 16;
    return v.f;
}
static __device__ __forceinline__ float wfull(const float* __restrict__ Wx,
                                              const float* __restrict__ Wh,
                                              int k, int col) {
    return (k < DD) ? Wx[(size_t)k * 4096 + col] : Wh[(size_t)(k - DD) * 4096 + col];
}
static __device__ __forceinline__ float sigmoidf_(float v) { return 1.0f / (1.0f + __expf(-v)); }

#define HLOAD(p) __hip_atomic_load((p), __ATOMIC_RELAXED, __HIP_MEMORY_SCOPE_AGENT)
#define HSTORE(p, v) __hip_atomic_store((p), (v), __ATOMIC_RELAXED, __HIP_MEMORY_SCOPE_AGENT)

__global__ void __launch_bounds__(512, 2)
lstm_mfma_flag(const float* __restrict__ x,
               const float* __restrict__ Wx,
               const float* __restrict__ Wh,
               const float* __restrict__ bias,
               float* __restrict__ out,
               unsigned* __restrict__ ws)
{
    cg::grid_group grid = cg::this_grid();

    __shared__ unsigned short sA[16][AP];   // 33 KB: staged A plane (x or h, hi or lo)
    __shared__ float sRed[8][16][17];       // 8.7 KB: per-wave partial C tiles
    __shared__ float sC[16][16];            // 1 KB: cell state (persists over t)

    unsigned* hp0   = ws;                   // packed h (hi<<16|lo), buffer 0: [64][1024]
    unsigned* hp1   = ws + 65536;           // buffer 1
    unsigned* flags = ws + 131072;          // [4][64] per-cohort progress flags

    const int tid  = threadIdx.x;
    const int lane = tid & 63;
    const int wid  = tid >> 6;         // 0..7
    const int ct   = wid & 3;          // col-tile
    const int kap  = wid >> 2;         // K-half
    const int bid  = blockIdx.x;
    const int rgrp = bid >> 6;         // cohort 0..3 (16 batch rows)
    const int cgrp = bid & 63;         // 0..63 (16 h-cols)
    const int rowbase = rgrp * 16;
    const int n  = lane & 15;          // MFMA A-row = B-col within tile
    const int kg = lane >> 4;          // k-group (8 contiguous k)

    // ---- one-time: weights into VGPR B-fragments, bf16 hi/lo split ----
    // wave's K ranges: x: kap*256+[0,256) ; h: 512 + kap*512 + [0,512)
    const int wcol = (n >> 2) * HH + cgrp * 16 + ct * 4 + (n & 3);
    sh8 bh[24], bl[24];
    #pragma unroll
    for (int f = 0; f < 24; ++f) {
        #pragma unroll
        for (int i = 0; i < 8; ++i) {
            const int k = (f < 8) ? (kap * 256 + f * 32 + kg * 8 + i)
                                  : (512 + kap * 512 + (f - 8) * 32 + kg * 8 + i);
            const float w = wfull(Wx, Wh, k, wcol);
            const unsigned short hi = f2bf(w);
            bh[f][i] = (short)hi;
            bl[f][i] = (short)f2bf(w - bf2f(hi));
        }
    }

    // ---- init: zero h_0 and flags (ws is poisoned 0xAA); one-time grid.sync ----
    {
        const int idx = bid * 512 + tid;
        if (idx < 65536) hp0[idx] = 0u;     // plain stores; grid.sync flushes them
        if (idx < 256)   flags[idx] = 0u;
    }
    if (tid < 256) sC[tid >> 4][tid & 15] = 0.0f;

    const int frow = lane >> 2, fjj = lane & 3;       // finalize lane -> (row, jj)
    const int gcol = cgrp * 16 + ct * 4 + fjj;
    float bg0 = 0.f, bg1 = 0.f, bg2 = 0.f, bg3 = 0.f;
    if (kap == 0) {
        bg0 = bias[0 * HH + gcol]; bg1 = bias[1 * HH + gcol];
        bg2 = bias[2 * HH + gcol]; bg3 = bias[3 * HH + gcol];
    }
    grid.sync();   // ONLY grid-wide sync: publishes zeroed hp0/flags everywhere

    for (int t = 0; t < TT; ++t) {
        const unsigned* hin  = (t & 1) ? hp1 : hp0;
        unsigned*       hout = (t & 1) ? hp0 : hp1;

        f32x4 acc0 = {0.f, 0.f, 0.f, 0.f}, acc1 = {0.f, 0.f, 0.f, 0.f};

        // ================= X phase (independent of h_t: overlaps barrier skew) =====
        // stage x hi
        #pragma unroll
        for (int p = 0; p < 4; ++p) {
            const int q = tid + p * 512;
            const int r = q >> 7, kq = (q & 127) * 4;
            const float4 v = *reinterpret_cast<const float4*>(
                &x[((size_t)(rowbase + r) * TT + t) * DD + kq]);
            ushort4 u;
            u.x = f2bf(v.x); u.y = f2bf(v.y); u.z = f2bf(v.z); u.w = f2bf(v.w);
            *reinterpret_cast<ushort4*>(&sA[r][kq]) = u;
        }
        __syncthreads();
        #pragma unroll
        for (int f = 0; f < 8; ++f) {
            const sh8 a = *reinterpret_cast<const sh8*>(&sA[n][kap * 256 + f * 32 + kg * 8]);
            if (f & 1) {
                acc1 = __builtin_amdgcn_mfma_f32_16x16x32_bf16(a, bh[f], acc1, 0, 0, 0);
                acc1 = __builtin_amdgcn_mfma_f32_16x16x32_bf16(a, bl[f], acc1, 0, 0, 0);
            } else {
                acc0 = __builtin_amdgcn_mfma_f32_16x16x32_bf16(a, bh[f], acc0, 0, 0, 0);
                acc0 = __builtin_amdgcn_mfma_f32_16x16x32_bf16(a, bl[f], acc0, 0, 0, 0);
            }
        }
        __syncthreads();
        // stage x lo
        #pragma unroll
        for (int p = 0; p < 4; ++p) {
            const int q = tid + p * 512;
            const int r = q >> 7, kq = (q & 127) * 4;
            const float4 v = *reinterpret_cast<const float4*>(
                &x[((size_t)(rowbase + r) * TT + t) * DD + kq]);
            ushort4 u;
            u.x = f2bf(v.x - bf2f(f2bf(v.x)));
            u.y = f2bf(v.y - bf2f(f2bf(v.y)));
            u.z = f2bf(v.z - bf2f(f2bf(v.z)));
            u.w = f2bf(v.w - bf2f(f2bf(v.w)));
            *reinterpret_cast<ushort4*>(&sA[r][kq]) = u;
        }
        __syncthreads();
        #pragma unroll
        for (int f = 0; f < 8; ++f) {
            const sh8 a = *reinterpret_cast<const sh8*>(&sA[n][kap * 256 + f * 32 + kg * 8]);
            if (f & 1) acc1 = __builtin_amdgcn_mfma_f32_16x16x32_bf16(a, bh[f], acc1, 0, 0, 0);
            else       acc0 = __builtin_amdgcn_mfma_f32_16x16x32_bf16(a, bh[f], acc0, 0, 0, 0);
        }

        // ================= cohort barrier: wait for h_t (64 flags, no atomics RMW) ==
        if (t > 0) {
            const unsigned tgt = (unsigned)t;
            while (true) {
                const unsigned v = HLOAD(&flags[rgrp * 64 + lane]);
                if (__all((int)(v >= tgt))) break;
                __builtin_amdgcn_s_sleep(2);
            }
        }
        asm volatile("" ::: "memory");   // compiler fence: no hoisting h loads above spin
        __syncthreads();                 // also closes x-lo MFMA reads of sA

        // ================= H phase: two passes over packed h ======================
        const unsigned* hrow = hin + (size_t)rowbase * HH;   // 16x1024 uints
        // pass hi
        #pragma unroll
        for (int c = 0; c < 8; ++c) {
            const int idx = c * 2048 + tid * 4;
            const int r = idx >> 10, kc = idx & 1023;
            const unsigned w0 = HLOAD(&hrow[idx + 0]);
            const unsigned w1 = HLOAD(&hrow[idx + 1]);
            const unsigned w2 = HLOAD(&hrow[idx + 2]);
            const unsigned w3 = HLOAD(&hrow[idx + 3]);
            ushort4 u;
            u.x = (unsigned short)(w0 >> 16); u.y = (unsigned short)(w1 >> 16);
            u.z = (unsigned short)(w2 >> 16); u.w = (unsigned short)(w3 >> 16);
            *reinterpret_cast<ushort4*>(&sA[r][kc]) = u;
        }
        __syncthreads();
        #pragma unroll
        for (int f = 8; f < 24; ++f) {
            const sh8 a = *reinterpret_cast<const sh8*>(
                &sA[n][kap * 512 + (f - 8) * 32 + kg * 8]);
            if (f & 1) {
                acc1 = __builtin_amdgcn_mfma_f32_16x16x32_bf16(a, bh[f], acc1, 0, 0, 0);
                acc1 = __builtin_amdgcn_mfma_f32_16x16x32_bf16(a, bl[f], acc1, 0, 0, 0);
            } else {
                acc0 = __builtin_amdgcn_mfma_f32_16x16x32_bf16(a, bh[f], acc0, 0, 0, 0);
                acc0 = __builtin_amdgcn_mfma_f32_16x16x32_bf16(a, bl[f], acc0, 0, 0, 0);
            }
        }
        __syncthreads();
        // pass lo
        #pragma unroll
        for (int c = 0; c < 8; ++c) {
            const int idx = c * 2048 + tid * 4;
            const int r = idx >> 10, kc = idx & 1023;
            const unsigned w0 = HLOAD(&hrow[idx + 0]);
            const unsigned w1 = HLOAD(&hrow[idx + 1]);
            const unsigned w2 = HLOAD(&hrow[idx + 2]);
            const unsigned w3 = HLOAD(&hrow[idx + 3]);
            ushort4 u;
            u.x = (unsigned short)(w0 & 0xFFFFu); u.y = (unsigned short)(w1 & 0xFFFFu);
            u.z = (unsigned short)(w2 & 0xFFFFu); u.w = (unsigned short)(w3 & 0xFFFFu);
            *reinterpret_cast<ushort4*>(&sA[r][kc]) = u;
        }
        __syncthreads();
        #pragma unroll
        for (int f = 8; f < 24; ++f) {
            const sh8 a = *reinterpret_cast<const sh8*>(
                &sA[n][kap * 512 + (f - 8) * 32 + kg * 8]);
            if (f & 1) acc1 = __builtin_amdgcn_mfma_f32_16x16x32_bf16(a, bh[f], acc1, 0, 0, 0);
            else       acc0 = __builtin_amdgcn_mfma_f32_16x16x32_bf16(a, bh[f], acc0, 0, 0, 0);
        }

        // ================= reduce K-halves + finalize =============================
        __syncthreads();   // closes h-lo MFMA reads of sA (sA rewritten next iter)
        #pragma unroll
        for (int q = 0; q < 4; ++q)
            sRed[wid][kg * 4 + q][n] = acc0[q] + acc1[q];   // C/D: col=lane&15, row=(lane>>4)*4+q
        __syncthreads();

        if (kap == 0) {
            const float pi = sRed[ct][frow][ 0 + fjj] + sRed[ct + 4][frow][ 0 + fjj] + bg0;
            const float pf = sRed[ct][frow][ 4 + fjj] + sRed[ct + 4][frow][ 4 + fjj] + bg1;
            const float pg = sRed[ct][frow][ 8 + fjj] + sRed[ct + 4][frow][ 8 + fjj] + bg2;
            const float po = sRed[ct][frow][12 + fjj] + sRed[ct + 4][frow][12 + fjj] + bg3;
            const float iv = sigmoidf_(pi);
            const float fv = sigmoidf_(pf);
            const float gv = tanhf(pg);
            const float ov = sigmoidf_(po);
            const float cold = sC[frow][ct * 4 + fjj];
            const float cn = fv * cold + iv * gv;
            const float hn = ov * tanhf(cn);
            sC[frow][ct * 4 + fjj] = cn;
            const int grow = rowbase + frow;
            out[((size_t)grow * TT + t) * HH + gcol] = hn;   // plain store (flushed at kernel end)
            const unsigned short hi = f2bf(hn);
            const unsigned short lo = f2bf(hn - bf2f(hi));
            HSTORE(&hout[grow * HH + gcol], ((unsigned)hi << 16) | (unsigned)lo);
        }
        __syncthreads();                 // s_barrier drains vmcnt: h stores are at MALL
        asm volatile("" ::: "memory");
        if (tid == 0) HSTORE(&flags[rgrp * 64 + cgrp], (unsigned)(t + 1));
    }
}

extern "C" void kernel_launch(void* const* d_in, const int* in_sizes, int n_in,
                              void* d_out, int out_size, void* d_ws, size_t ws_size,
                              hipStream_t stream) {
    const float* x  = (const float*)d_in[0];
    const float* Wx = (const float*)d_in[1];
    const float* Wh = (const float*)d_in[2];
    const float* b  = (const float*)d_in[3];
    float* out = (float*)d_out;
    unsigned* ws = (unsigned*)d_ws;   // needs (2*64*1024 + 256)*4 B ≈ 513 KB

    void* args[] = { (void*)&x, (void*)&Wx, (void*)&Wh, (void*)&b,
                     (void*)&out, (void*)&ws };
    hipLaunchCooperativeKernel((const void*)lstm_mfma_flag,
                               dim3(256), dim3(512), args, 0, stream);
}

// Round 7
// 5140.694 us; speedup vs baseline: 16.2828x; 1.4373x over previous
//
#include <hip/hip_runtime.h>
#include <hip/hip_cooperative_groups.h>

namespace cg = cooperative_groups;

// LSTM B=64,T=512,D=512,H=1024 ; gates 4H=4096 ; K = D+H = 1536
// 256 blocks = 4 row-cohorts (16 batch rows) x 64 col-groups (16 h-cols).
// Weights in per-wave B-fragments (bf16 hi/lo split), loaded ONCE.
// 8 waves = (col-tile ct 0..3) x (K-half kap 0..1).
// Sync protocol = round-5 (HW-validated): per-cohort flag barrier, packed-h
// exchange via agent-scope (sc0 sc1) per-access atomics, no cache flushes.
// New in v7: h read ONCE per step with coalesced 8B coherent loads (hi->LDS,
// lo->16 VGPRs); x read once (hi->LDS, lo->8 VGPRs); two MFMA passes over a
// single 49.4 KB A-plane; restage lo from registers between passes.
// HARD CONSTRAINT (rounds 2/6 failures): static LDS must stay < 64 KB.
#define BB 64
#define TT 512
#define DD 512
#define HH 1024
#define AP 1544   // shorts per A row: [x 0..512 | h 512..1536] + 8 pad (row stride 3088B)

typedef __attribute__((ext_vector_type(8))) short sh8;   // 8 bf16 (MFMA A/B frag)
typedef __attribute__((ext_vector_type(4))) float f32x4; // MFMA C/D frag
typedef unsigned long long ull;

static __device__ __forceinline__ unsigned short f2bf(float f) {   // RNE f32->bf16
    union { float f; unsigned u; } v; v.f = f;
    unsigned r = v.u + 0x7FFF + ((v.u >> 16) & 1);
    return (unsigned short)(r >> 16);
}
static __device__ __forceinline__ float bf2f(unsigned short h) {
    union { unsigned u; float f; } v; v.u = ((unsigned)h) << 16;
    return v.f;
}
static __device__ __forceinline__ float wfull(const float* __restrict__ Wx,
                                              const float* __restrict__ Wh,
                                              int k, int col) {
    return (k < DD) ? Wx[(size_t)k * 4096 + col] : Wh[(size_t)(k - DD) * 4096 + col];
}
static __device__ __forceinline__ float sigmoidf_(float v) { return 1.0f / (1.0f + __expf(-v)); }

#define HLOAD(p)     __hip_atomic_load((p), __ATOMIC_RELAXED, __HIP_MEMORY_SCOPE_AGENT)
#define HSTORE(p, v) __hip_atomic_store((p), (v), __ATOMIC_RELAXED, __HIP_MEMORY_SCOPE_AGENT)

__global__ void __launch_bounds__(512, 2)
lstm_mfma_v7(const float* __restrict__ x,
             const float* __restrict__ Wx,
             const float* __restrict__ Wh,
             const float* __restrict__ bias,
             float* __restrict__ out,
             unsigned* __restrict__ ws)
{
    cg::grid_group grid = cg::this_grid();

    __shared__ unsigned short sA[16][AP];   // 49.4 KB: A plane (hi pass, then lo pass)
    __shared__ float sRed[8][16][17];       // 8.7 KB: per-wave partial C tiles
    __shared__ float sC[16][16];            // 1 KB: cell state (persists over t)
    // total static LDS ~59.1 KB  (< 64 KB hard limit)

    unsigned* hp0   = ws;                   // packed h (hi<<16|lo), buffer 0: [64][1024]
    unsigned* hp1   = ws + 65536;           // buffer 1
    unsigned* flags = ws + 131072;          // [4][64] per-cohort progress flags

    const int tid  = threadIdx.x;
    const int lane = tid & 63;
    const int wid  = tid >> 6;         // 0..7
    const int ct   = wid & 3;          // col-tile
    const int kap  = wid >> 2;         // K-half
    const int bid  = blockIdx.x;
    const int rgrp = bid >> 6;         // cohort 0..3 (16 batch rows)
    const int cgrp = bid & 63;         // 0..63 (16 h-cols)
    const int rowbase = rgrp * 16;
    const int n  = lane & 15;          // MFMA A-row = B-col within tile
    const int kg = lane >> 4;          // k-group (8 contiguous k)

    // ---- one-time: weights into B-fragments, bf16 hi/lo split ----
    // wave's K ranges: x: kap*256+[0,256) ; h: 512 + kap*512 + [0,512)
    const int wcol = (n >> 2) * HH + cgrp * 16 + ct * 4 + (n & 3);
    sh8 bh[24], bl[24];
    #pragma unroll
    for (int f = 0; f < 24; ++f) {
        #pragma unroll
        for (int i = 0; i < 8; ++i) {
            const int k = (f < 8) ? (kap * 256 + f * 32 + kg * 8 + i)
                                  : (512 + kap * 512 + (f - 8) * 32 + kg * 8 + i);
            const float w = wfull(Wx, Wh, k, wcol);
            const unsigned short hi = f2bf(w);
            bh[f][i] = (short)hi;
            bl[f][i] = (short)f2bf(w - bf2f(hi));
        }
    }

    // ---- init: zero h_0 and flags (ws is poisoned 0xAA); one-time grid.sync ----
    {
        const int idx = bid * 512 + tid;
        if (idx < 65536) hp0[idx] = 0u;
        if (idx < 256)   flags[idx] = 0u;
    }
    if (tid < 256) sC[tid >> 4][tid & 15] = 0.0f;

    const int frow = lane >> 2, fjj = lane & 3;       // finalize lane -> (row, jj)
    const int gcol = cgrp * 16 + ct * 4 + fjj;
    float bg0 = 0.f, bg1 = 0.f, bg2 = 0.f, bg3 = 0.f;
    if (kap == 0) {
        bg0 = bias[0 * HH + gcol]; bg1 = bias[1 * HH + gcol];
        bg2 = bias[2 * HH + gcol]; bg3 = bias[3 * HH + gcol];
    }
    grid.sync();   // ONLY grid-wide sync: publishes zeroed hp0/flags everywhere

    for (int t = 0; t < TT; ++t) {
        const unsigned* hin  = (t & 1) ? hp1 : hp0;
        unsigned*       hout = (t & 1) ? hp0 : hp1;

        // ---- stage x hi -> LDS, keep x lo packed in 8 VGPRs (overlaps barrier) ----
        unsigned xlo[8];
        #pragma unroll
        for (int p = 0; p < 4; ++p) {
            const int q = tid + p * 512;
            const int r = q >> 7, kq = (q & 127) * 4;
            const float4 v = *reinterpret_cast<const float4*>(
                &x[((size_t)(rowbase + r) * TT + t) * DD + kq]);
            ushort4 uh;
            unsigned l01, l23;
            uh.x = f2bf(v.x); l01  = (unsigned)f2bf(v.x - bf2f(uh.x));
            uh.y = f2bf(v.y); l01 |= ((unsigned)f2bf(v.y - bf2f(uh.y))) << 16;
            uh.z = f2bf(v.z); l23  = (unsigned)f2bf(v.z - bf2f(uh.z));
            uh.w = f2bf(v.w); l23 |= ((unsigned)f2bf(v.w - bf2f(uh.w))) << 16;
            *reinterpret_cast<ushort4*>(&sA[r][kq]) = uh;
            xlo[2 * p] = l01; xlo[2 * p + 1] = l23;
        }

        // ---- cohort barrier: wait for h_t (64 flags, lane-parallel poll) ----
        if (t > 0) {
            const unsigned tgt = (unsigned)t;
            while (true) {
                const unsigned v = HLOAD(&flags[rgrp * 64 + lane]);
                if (__all((int)(v >= tgt))) break;
                __builtin_amdgcn_s_sleep(2);
            }
        }
        asm volatile("" ::: "memory");   // no hoisting h loads above the spin

        // ---- stage h ONCE: 16 coalesced 8B coherent loads; hi->LDS, lo->16 VGPRs ----
        unsigned hlo[16];
        {
            const ull* hq = reinterpret_cast<const ull*>(hin + (size_t)rowbase * HH);
            #pragma unroll
            for (int i = 0; i < 16; ++i) {
                const ull w = HLOAD(&hq[i * 512 + tid]);     // row i, elements 2*tid, 2*tid+1
                const unsigned u0 = (unsigned)w;
                const unsigned u1 = (unsigned)(w >> 32);
                *reinterpret_cast<unsigned*>(&sA[i][512 + tid * 2]) =
                    (u0 >> 16) | (u1 & 0xFFFF0000u);
                hlo[i] = (u0 & 0xFFFFu) | (u1 << 16);
            }
        }
        __syncthreads();   // S1: hi plane fully staged

        // ---- MFMA pass 1: acc += Ah*Bh + Ah*Bl  (48 MFMAs) ----
        f32x4 acc0 = {0.f, 0.f, 0.f, 0.f}, acc1 = {0.f, 0.f, 0.f, 0.f};
        #pragma unroll
        for (int f = 0; f < 24; ++f) {
            const int k = (f < 8) ? (kap * 256 + f * 32 + kg * 8)
                                  : (512 + kap * 512 + (f - 8) * 32 + kg * 8);
            const sh8 ah = *reinterpret_cast<const sh8*>(&sA[n][k]);
            if (f & 1) {
                acc1 = __builtin_amdgcn_mfma_f32_16x16x32_bf16(ah, bh[f], acc1, 0, 0, 0);
                acc1 = __builtin_amdgcn_mfma_f32_16x16x32_bf16(ah, bl[f], acc1, 0, 0, 0);
            } else {
                acc0 = __builtin_amdgcn_mfma_f32_16x16x32_bf16(ah, bh[f], acc0, 0, 0, 0);
                acc0 = __builtin_amdgcn_mfma_f32_16x16x32_bf16(ah, bl[f], acc0, 0, 0, 0);
            }
        }
        __syncthreads();   // S2: all hi-plane reads retired

        // ---- restage lo plane from registers (no memory traffic) ----
        #pragma unroll
        for (int p = 0; p < 4; ++p) {
            const int q = tid + p * 512;
            const int r = q >> 7, kq = (q & 127) * 4;
            unsigned* d = reinterpret_cast<unsigned*>(&sA[r][kq]);
            d[0] = xlo[2 * p]; d[1] = xlo[2 * p + 1];
        }
        #pragma unroll
        for (int i = 0; i < 16; ++i)
            *reinterpret_cast<unsigned*>(&sA[i][512 + tid * 2]) = hlo[i];
        __syncthreads();   // S3: lo plane staged

        // ---- MFMA pass 2: acc += Al*Bh  (24 MFMAs) ----
        #pragma unroll
        for (int f = 0; f < 24; ++f) {
            const int k = (f < 8) ? (kap * 256 + f * 32 + kg * 8)
                                  : (512 + kap * 512 + (f - 8) * 32 + kg * 8);
            const sh8 al = *reinterpret_cast<const sh8*>(&sA[n][k]);
            if (f & 1) acc1 = __builtin_amdgcn_mfma_f32_16x16x32_bf16(al, bh[f], acc1, 0, 0, 0);
            else       acc0 = __builtin_amdgcn_mfma_f32_16x16x32_bf16(al, bh[f], acc0, 0, 0, 0);
        }

        // ---- reduce K-halves + finalize ----
        #pragma unroll
        for (int q = 0; q < 4; ++q)
            sRed[wid][kg * 4 + q][n] = acc0[q] + acc1[q];   // C/D: col=lane&15, row=(lane>>4)*4+q
        __syncthreads();   // S4: sRed complete; also closes pass-2 sA reads

        if (kap == 0) {
            const float pi = sRed[ct][frow][ 0 + fjj] + sRed[ct + 4][frow][ 0 + fjj] + bg0;
            const float pf = sRed[ct][frow][ 4 + fjj] + sRed[ct + 4][frow][ 4 + fjj] + bg1;
            const float pg = sRed[ct][frow][ 8 + fjj] + sRed[ct + 4][frow][ 8 + fjj] + bg2;
            const float po = sRed[ct][frow][12 + fjj] + sRed[ct + 4][frow][12 + fjj] + bg3;
            const float iv = sigmoidf_(pi);
            const float fv = sigmoidf_(pf);
            const float gv = tanhf(pg);
            const float ov = sigmoidf_(po);
            const float cold = sC[frow][ct * 4 + fjj];
            const float cn = fv * cold + iv * gv;
            const float hn = ov * tanhf(cn);
            sC[frow][ct * 4 + fjj] = cn;
            const int grow = rowbase + frow;
            out[((size_t)grow * TT + t) * HH + gcol] = hn;   // plain store (flushed at kernel end)
            const unsigned short hi = f2bf(hn);
            const unsigned short lo = f2bf(hn - bf2f(hi));
            HSTORE(&hout[grow * HH + gcol], ((unsigned)hi << 16) | (unsigned)lo);
        }
        __syncthreads();                 // S5: drains vmcnt -> h stores ack'd at coherence point
        asm volatile("" ::: "memory");
        if (tid == 0) HSTORE(&flags[rgrp * 64 + cgrp], (unsigned)(t + 1));
    }
}

extern "C" void kernel_launch(void* const* d_in, const int* in_sizes, int n_in,
                              void* d_out, int out_size, void* d_ws, size_t ws_size,
                              hipStream_t stream) {
    const float* x  = (const float*)d_in[0];
    const float* Wx = (const float*)d_in[1];
    const float* Wh = (const float*)d_in[2];
    const float* b  = (const float*)d_in[3];
    float* out = (float*)d_out;
    unsigned* ws = (unsigned*)d_ws;   // needs (2*64*1024 + 256)*4 B ≈ 513 KB

    void* args[] = { (void*)&x, (void*)&Wx, (void*)&Wh, (void*)&b,
                     (void*)&out, (void*)&ws };
    hipLaunchCooperativeKernel((const void*)lstm_mfma_v7,
                               dim3(256), dim3(512), args, 0, stream);
}